// Round 1
// baseline (184.001 us; speedup 1.0000x reference)
//
#include <hip/hip_runtime.h>
#include <cstddef>

// Problem constants (from reference): B=4, N=4096, D=128, R=4, K=16, O=128
namespace {
constexpr int B_ = 4, N_ = 4096, D_ = 128, R_ = 4, K_ = 16, O_ = 128;
constexpr int TN = 16;                 // nodes per block
constexpr int THREADS = 256;
constexpr int KK = (R_ + 1) * D_;      // 640 stacked-K (4 relations + self)
constexpr int PITCH = KK + 8;          // 648 floats: 16B-aligned rows, breaks pow-2 stride
}

__global__ __launch_bounds__(THREADS)
void gcn_fused(const float* __restrict__ nf,     // [B][N][D]
               const int*   __restrict__ nbr,    // [B][R][N][K], 0 = zero-pad, i+1 = node i
               const float* __restrict__ relk,   // [R][D][O]
               const float* __restrict__ selfk,  // [D][O]
               const float* __restrict__ bias,   // [O]
               float*       __restrict__ out)    // [B][N][O]
{
    __shared__ float agg[TN][PITCH];   // agg[n][r*128+d], r=4 is self features

    const int bid  = blockIdx.x;
    const int b    = bid / (N_ / TN);
    const int n0   = (bid % (N_ / TN)) * TN;
    const int tid  = threadIdx.x;
    const int lane = tid & 31;         // float4 slot within a 128-float row
    const int grp  = tid >> 5;         // 8 groups of 32 lanes

    // ---- Phase 1: gather + mean over K for each (relation, node) ----
    // 64 (r,n) pairs; each 32-lane group owns 8 of them. Index is uniform
    // across the group -> broadcast load; row read is 32 lanes x float4 = 512B.
    for (int p = grp; p < R_ * TN; p += THREADS / 32) {
        const int r = p >> 4;              // TN == 16
        const int n = p & (TN - 1);
        const int* idxp = nbr + (((size_t)b * R_ + r) * N_ + (n0 + n)) * K_;
        float4 acc = make_float4(0.f, 0.f, 0.f, 0.f);
        #pragma unroll
        for (int k = 0; k < K_; ++k) {
            const int idx = idxp[k];
            if (idx != 0) {  // idx 0 == zero pad row: contributes nothing
                const float4 v =
                    ((const float4*)(nf + ((size_t)b * N_ + (idx - 1)) * D_))[lane];
                acc.x += v.x; acc.y += v.y; acc.z += v.z; acc.w += v.w;
            }
        }
        constexpr float s = 1.0f / (float)K_;
        float4 res = make_float4(acc.x * s, acc.y * s, acc.z * s, acc.w * s);
        *(float4*)&agg[n][r * D_ + lane * 4] = res;
    }
    // self features -> agg[n][4*D + d]
    for (int t = tid; t < TN * (D_ / 4); t += THREADS) {
        const int n = t >> 5;
        const int q = t & 31;
        const float4 v = ((const float4*)(nf + ((size_t)b * N_ + n0 + n) * D_))[q];
        *(float4*)&agg[n][R_ * D_ + q * 4] = v;
    }
    __syncthreads();

    // ---- Phase 2: out[n][o] = relu(sum_kk agg[n][kk] * W[kk][o] + bias[o]) ----
    // W stacked: kk<512 -> relk[kk][o]; kk>=512 -> selfk[kk-512][o].
    // Thread tile: 2 nodes x 4 outputs. Within a wave, half-waves read two
    // distinct agg rows (broadcast each, no bank conflict); W float4 loads are
    // 512B-coalesced per half-wave and L1/L2 resident (320 KB total).
    const int og = tid & 31;           // o = og*4 .. og*4+3
    const int ng = tid >> 5;           // n = ng*2 + {0,1}
    float acc[2][4] = {};
    const float* __restrict__ aw0 = &agg[ng * 2 + 0][0];
    const float* __restrict__ aw1 = &agg[ng * 2 + 1][0];
    for (int kk4 = 0; kk4 < KK; kk4 += 4) {
        const float4 a0 = *(const float4*)(aw0 + kk4);
        const float4 a1 = *(const float4*)(aw1 + kk4);
        const float* wbase = (kk4 < R_ * D_)
                                 ? (relk + (size_t)kk4 * O_)
                                 : (selfk + (size_t)(kk4 - R_ * D_) * O_);
        #pragma unroll
        for (int t = 0; t < 4; ++t) {
            const float4 w = *(const float4*)(wbase + t * O_ + og * 4);
            const float a0t = (&a0.x)[t];
            const float a1t = (&a1.x)[t];
            acc[0][0] += a0t * w.x; acc[0][1] += a0t * w.y;
            acc[0][2] += a0t * w.z; acc[0][3] += a0t * w.w;
            acc[1][0] += a1t * w.x; acc[1][1] += a1t * w.y;
            acc[1][2] += a1t * w.z; acc[1][3] += a1t * w.w;
        }
    }
    const float4 bv = *(const float4*)(bias + og * 4);
    #pragma unroll
    for (int i = 0; i < 2; ++i) {
        const int n = ng * 2 + i;
        float4 o4;
        o4.x = fmaxf(acc[i][0] + bv.x, 0.f);
        o4.y = fmaxf(acc[i][1] + bv.y, 0.f);
        o4.z = fmaxf(acc[i][2] + bv.z, 0.f);
        o4.w = fmaxf(acc[i][3] + bv.w, 0.f);
        *(float4*)(out + ((size_t)b * N_ + n0 + n) * O_ + og * 4) = o4;
    }
}

extern "C" void kernel_launch(void* const* d_in, const int* in_sizes, int n_in,
                              void* d_out, int out_size, void* d_ws, size_t ws_size,
                              hipStream_t stream) {
    const float* nf    = (const float*)d_in[0];  // node_features  [B,N,D] f32
    const int*   nbr   = (const int*)  d_in[1];  // neighbor_indices [B,R,N,K] i32
    const float* relk  = (const float*)d_in[2];  // relation_kernels [R,D,O] f32
    const float* selfk = (const float*)d_in[3];  // self_kernel [D,O] f32
    const float* bias  = (const float*)d_in[4];  // bias [O] f32
    float* outp = (float*)d_out;                 // [B,N,O] f32

    dim3 grid(B_ * (N_ / TN));
    gcn_fused<<<grid, THREADS, 0, stream>>>(nf, nbr, relk, selfk, bias, outp);
}

// Round 2
// 131.325 us; speedup vs baseline: 1.4011x; 1.4011x over previous
//
#include <hip/hip_runtime.h>
#include <cstddef>

// Problem constants (from reference): B=4, N=4096, D=128, R=4, K=16, O=128
namespace {
constexpr int B_ = 4, N_ = 4096, D_ = 128, R_ = 4, K_ = 16, O_ = 128;
constexpr int TN = 16;                 // nodes per block
constexpr int THREADS = 256;
constexpr int KK = (R_ + 1) * D_;      // 640 stacked-K (4 relations + self)
constexpr int PITCH = KK;              // 640 floats; phase-2 reads are broadcasts,
                                       // phase-1 writes contiguous b128 -> no pad needed.
                                       // LDS = 16*640*4 = 40960 B -> exactly 4 blocks/CU.
}

__global__ __launch_bounds__(THREADS, 4)
void gcn_fused(const float* __restrict__ nf,     // [B][N][D]
               const int*   __restrict__ nbr,    // [B][R][N][K], 0 = zero-pad, i+1 = node i
               const float* __restrict__ relk,   // [R][D][O]
               const float* __restrict__ selfk,  // [D][O]
               const float* __restrict__ bias,   // [O]
               float*       __restrict__ out)    // [B][N][O]
{
    __shared__ float agg[TN][PITCH];   // agg[n][r*128+d], r=4 is self features

    const int bid  = blockIdx.x;
    const int b    = bid / (N_ / TN);
    const int n0   = (bid % (N_ / TN)) * TN;
    const int tid  = threadIdx.x;
    const int lane = tid & 31;         // float4 slot within a 128-float row
    const int g    = tid >> 5;         // 8 groups of 32 lanes
    const int lhalf = g & 1;           // which half of the wave this group is

    // ---- Phase 1: gather + mean over K ----
    // Group g owns 8 consecutive (r,n) pairs: r = g>>1, nodes nb..nb+7.
    // All 8*16 = 128 indices are CONTIGUOUS -> one coalesced int4 load per
    // group; distribute via __shfl. Row loads are branchless (pad row -> *0).
    {
        const int r  = g >> 1;
        const int nb = (g & 1) * 8;
        const int* idx_start = nbr + (((size_t)b * R_ + r) * N_ + (n0 + nb)) * K_;
        const int4 idxv = ((const int4*)idx_start)[lane];   // lane l: idx[4l..4l+3]

        const float* __restrict__ nfb = nf + (size_t)b * N_ * D_;

        #pragma unroll 2
        for (int i = 0; i < 8; ++i) {
            float4 acc0 = make_float4(0.f, 0.f, 0.f, 0.f);
            float4 acc1 = make_float4(0.f, 0.f, 0.f, 0.f);
            #pragma unroll
            for (int k = 0; k < K_; ++k) {
                const int src = lhalf * 32 + i * 4 + (k >> 2);
                int idx;
                switch (k & 3) {
                    case 0: idx = __shfl(idxv.x, src, 64); break;
                    case 1: idx = __shfl(idxv.y, src, 64); break;
                    case 2: idx = __shfl(idxv.z, src, 64); break;
                    default: idx = __shfl(idxv.w, src, 64); break;
                }
                const float m  = (idx != 0) ? (1.0f / (float)K_) : 0.0f;
                const int row  = (idx != 0) ? (idx - 1) : 0;
                const float4 v = ((const float4*)(nfb + (size_t)row * D_))[lane];
                float4& a = (k & 1) ? acc1 : acc0;
                a.x = fmaf(v.x, m, a.x);
                a.y = fmaf(v.y, m, a.y);
                a.z = fmaf(v.z, m, a.z);
                a.w = fmaf(v.w, m, a.w);
            }
            float4 res = make_float4(acc0.x + acc1.x, acc0.y + acc1.y,
                                     acc0.z + acc1.z, acc0.w + acc1.w);
            *(float4*)&agg[nb + i][r * D_ + lane * 4] = res;
        }
    }
    // self features -> agg[n][4*D + d]
    for (int t = tid; t < TN * (D_ / 4); t += THREADS) {
        const int n = t >> 5;
        const int q = t & 31;
        const float4 v = ((const float4*)(nf + ((size_t)b * N_ + n0 + n) * D_))[q];
        *(float4*)&agg[n][R_ * D_ + q * 4] = v;
    }
    __syncthreads();

    // ---- Phase 2: out[n][o] = relu(sum_kk agg[n][kk] * W[kk][o] + bias[o]) ----
    // Thread tile: 2 nodes x 4 outputs. agg reads are half-wave broadcasts
    // (no bank conflicts regardless of pitch); W float4 loads are coalesced
    // and L2-resident (320 KB total).
    const int og = tid & 31;           // o = og*4 .. og*4+3
    const int ng = tid >> 5;           // n = ng*2 + {0,1}
    float acc[2][4] = {};
    const float* __restrict__ aw0 = &agg[ng * 2 + 0][0];
    const float* __restrict__ aw1 = &agg[ng * 2 + 1][0];

    #pragma unroll 4
    for (int kk4 = 0; kk4 < R_ * D_; kk4 += 4) {
        const float4 a0 = *(const float4*)(aw0 + kk4);
        const float4 a1 = *(const float4*)(aw1 + kk4);
        const float* wbase = relk + (size_t)kk4 * O_;
        #pragma unroll
        for (int t = 0; t < 4; ++t) {
            const float4 w = *(const float4*)(wbase + t * O_ + og * 4);
            const float a0t = (&a0.x)[t];
            const float a1t = (&a1.x)[t];
            acc[0][0] = fmaf(a0t, w.x, acc[0][0]); acc[0][1] = fmaf(a0t, w.y, acc[0][1]);
            acc[0][2] = fmaf(a0t, w.z, acc[0][2]); acc[0][3] = fmaf(a0t, w.w, acc[0][3]);
            acc[1][0] = fmaf(a1t, w.x, acc[1][0]); acc[1][1] = fmaf(a1t, w.y, acc[1][1]);
            acc[1][2] = fmaf(a1t, w.z, acc[1][2]); acc[1][3] = fmaf(a1t, w.w, acc[1][3]);
        }
    }
    #pragma unroll 4
    for (int kk4 = 0; kk4 < D_; kk4 += 4) {
        const float4 a0 = *(const float4*)(aw0 + R_ * D_ + kk4);
        const float4 a1 = *(const float4*)(aw1 + R_ * D_ + kk4);
        const float* wbase = selfk + (size_t)kk4 * O_;
        #pragma unroll
        for (int t = 0; t < 4; ++t) {
            const float4 w = *(const float4*)(wbase + t * O_ + og * 4);
            const float a0t = (&a0.x)[t];
            const float a1t = (&a1.x)[t];
            acc[0][0] = fmaf(a0t, w.x, acc[0][0]); acc[0][1] = fmaf(a0t, w.y, acc[0][1]);
            acc[0][2] = fmaf(a0t, w.z, acc[0][2]); acc[0][3] = fmaf(a0t, w.w, acc[0][3]);
            acc[1][0] = fmaf(a1t, w.x, acc[1][0]); acc[1][1] = fmaf(a1t, w.y, acc[1][1]);
            acc[1][2] = fmaf(a1t, w.z, acc[1][2]); acc[1][3] = fmaf(a1t, w.w, acc[1][3]);
        }
    }

    const float4 bv = *(const float4*)(bias + og * 4);
    #pragma unroll
    for (int i = 0; i < 2; ++i) {
        const int n = ng * 2 + i;
        float4 o4;
        o4.x = fmaxf(acc[i][0] + bv.x, 0.f);
        o4.y = fmaxf(acc[i][1] + bv.y, 0.f);
        o4.z = fmaxf(acc[i][2] + bv.z, 0.f);
        o4.w = fmaxf(acc[i][3] + bv.w, 0.f);
        *(float4*)(out + ((size_t)b * N_ + n0 + n) * O_ + og * 4) = o4;
    }
}

extern "C" void kernel_launch(void* const* d_in, const int* in_sizes, int n_in,
                              void* d_out, int out_size, void* d_ws, size_t ws_size,
                              hipStream_t stream) {
    const float* nf    = (const float*)d_in[0];  // node_features  [B,N,D] f32
    const int*   nbr   = (const int*)  d_in[1];  // neighbor_indices [B,R,N,K] i32
    const float* relk  = (const float*)d_in[2];  // relation_kernels [R,D,O] f32
    const float* selfk = (const float*)d_in[3];  // self_kernel [D,O] f32
    const float* bias  = (const float*)d_in[4];  // bias [O] f32
    float* outp = (float*)d_out;                 // [B,N,O] f32

    dim3 grid(B_ * (N_ / TN));
    gcn_fused<<<grid, THREADS, 0, stream>>>(nf, nbr, relk, selfk, bias, outp);
}

// Round 3
// 47.774 us; speedup vs baseline: 3.8515x; 2.7489x over previous
//
#include <hip/hip_runtime.h>
#include <cstddef>

// Problem constants (from reference): B=4, N=4096, D=128, R=4, K=16, O=128
namespace {
constexpr int B_ = 4, N_ = 4096, D_ = 128, R_ = 4, K_ = 16, O_ = 128;
constexpr int NP1 = N_ + 1;            // padded table rows (row 0 = zeros)
constexpr int TN = 16;                 // nodes per block (MFMA M)
constexpr int THREADS = 256;
constexpr int KK = (R_ + 1) * D_;      // 640 stacked-K (4 relations + self)
constexpr int PITCH_A = KK + 8;        // 648 bf16 -> row stride 1296B = 324 words,
                                       // 324 % 32 == 4 -> max 2-way bank alias (free)
}

typedef __bf16 bf16x8 __attribute__((ext_vector_type(8)));
typedef __bf16 bf16x4 __attribute__((ext_vector_type(4)));
typedef float  f32x4v __attribute__((ext_vector_type(4)));

// ---- prep 1: fp32 features -> bf16 padded table ws[B][NP1][D], row 0 = 0 ----
__global__ __launch_bounds__(256)
void prep_table(const float* __restrict__ nf, __bf16* __restrict__ ptab) {
    const int c = blockIdx.x * 256 + threadIdx.x;        // one bf16x4 chunk
    const int total = B_ * NP1 * (D_ / 4);
    if (c >= total) return;
    const int b   = c / (NP1 * 32);
    const int rem = c % (NP1 * 32);
    const int row = rem >> 5;
    const int q   = rem & 31;
    bf16x4 res;
    if (row == 0) {
        res[0] = (__bf16)0.f; res[1] = (__bf16)0.f;
        res[2] = (__bf16)0.f; res[3] = (__bf16)0.f;
    } else {
        const float4 v = *(const float4*)(nf + ((size_t)b * N_ + (row - 1)) * D_ + q * 4);
        res[0] = (__bf16)v.x; res[1] = (__bf16)v.y;
        res[2] = (__bf16)v.z; res[3] = (__bf16)v.w;
    }
    *(bf16x4*)(ptab + ((size_t)b * NP1 + row) * D_ + q * 4) = res;
}

// ---- prep 2: stacked W [640][128] -> transposed bf16 Wt[128][640] ----
__global__ __launch_bounds__(256)
void prep_wt(const float* __restrict__ relk, const float* __restrict__ selfk,
             __bf16* __restrict__ wt) {
    const int t = blockIdx.x * 256 + threadIdx.x;
    if (t >= O_ * KK) return;
    const int o  = t / KK;
    const int kk = t % KK;
    const float w = (kk < R_ * D_) ? relk[(size_t)kk * O_ + o]
                                   : selfk[(size_t)(kk - R_ * D_) * O_ + o];
    wt[(size_t)o * KK + kk] = (__bf16)w;
}

// ---- main: gather+mean (bf16, L2-resident) then MFMA matmul ----
__global__ __launch_bounds__(THREADS, 4)
void gcn_fused(const __bf16* __restrict__ ptab,  // [B][NP1][D] bf16, row0=0
               const int*    __restrict__ nbr,   // [B][R][N][K]
               const __bf16* __restrict__ wt,    // [O][KK] bf16 (W^T stacked)
               const float*  __restrict__ bias,  // [O]
               float*        __restrict__ out)   // [B][N][O]
{
    __shared__ __bf16 agg[TN][PITCH_A];          // 16 x 648 bf16 = 20736 B

    // batch<->XCD affinity: XCD pair {2b,2b+1} serves batch b only, so each
    // XCD's gather working set is one 1.05 MB bf16 table (L2-resident).
    const int hw   = blockIdx.x;
    const int xcd  = hw & 7;
    const int b    = xcd >> 1;
    const int tile = (xcd & 1) + ((hw >> 3) << 1);   // 0..255 within batch
    const int n0   = tile * TN;

    const int tid    = threadIdx.x;
    const int lane32 = tid & 31;

    // ---- Phase 1: gather + mean over K ----
    // Group g (32 lanes) owns r = g>>1, nodes nb..nb+7. Its 128 indices are
    // contiguous -> one int4/lane coalesced load, distributed via __shfl.
    // Pad row 0 is real zeros -> fully branchless.
    {
        const int g  = tid >> 5;
        const int r  = g >> 1;
        const int nb = (g & 1) * 8;
        const int* idx_start = nbr + (((size_t)b * R_ + r) * N_ + (n0 + nb)) * K_;
        const int4 idxv = ((const int4*)idx_start)[lane32];
        const __bf16* __restrict__ tb = ptab + (size_t)b * NP1 * D_;

        #pragma unroll 2
        for (int i = 0; i < 8; ++i) {
            float ac0[4] = {0.f, 0.f, 0.f, 0.f};
            float ac1[4] = {0.f, 0.f, 0.f, 0.f};
            #pragma unroll
            for (int k = 0; k < K_; ++k) {
                const int src = (g & 1) * 32 + i * 4 + (k >> 2);
                int idx;
                switch (k & 3) {
                    case 0:  idx = __shfl(idxv.x, src, 64); break;
                    case 1:  idx = __shfl(idxv.y, src, 64); break;
                    case 2:  idx = __shfl(idxv.z, src, 64); break;
                    default: idx = __shfl(idxv.w, src, 64); break;
                }
                const bf16x4 v = *(const bf16x4*)(tb + (size_t)idx * D_ + lane32 * 4);
                float* a = (k & 1) ? ac1 : ac0;
                a[0] += (float)v[0]; a[1] += (float)v[1];
                a[2] += (float)v[2]; a[3] += (float)v[3];
            }
            constexpr float s = 1.0f / (float)K_;
            bf16x4 res;
            res[0] = (__bf16)((ac0[0] + ac1[0]) * s);
            res[1] = (__bf16)((ac0[1] + ac1[1]) * s);
            res[2] = (__bf16)((ac0[2] + ac1[2]) * s);
            res[3] = (__bf16)((ac0[3] + ac1[3]) * s);
            *(bf16x4*)&agg[nb + i][r * D_ + lane32 * 4] = res;
        }
    }
    // self features: copy bf16 row (idx n0+n maps to table row n0+n+1)
    for (int t = tid; t < TN * 32; t += THREADS) {
        const int n = t >> 5;
        const int q = t & 31;
        const bf16x4 v = *(const bf16x4*)(ptab + ((size_t)b * NP1 + n0 + n + 1) * D_ + q * 4);
        *(bf16x4*)&agg[n][R_ * D_ + q * 4] = v;
    }
    __syncthreads();

    // ---- Phase 2: MFMA. Per wave: 16x32 output (2 col-tiles), K = 640. ----
    const int wv = tid >> 6;             // 0..3
    const int l  = tid & 63;
    const int lr = l & 15;               // A row / B col / C col
    const int lk = l >> 4;               // k-group
    const int ct0 = wv * 2, ct1 = wv * 2 + 1;

    const __bf16* __restrict__ wr0 = wt + (size_t)(ct0 * 16 + lr) * KK + lk * 8;
    const __bf16* __restrict__ wr1 = wt + (size_t)(ct1 * 16 + lr) * KK + lk * 8;
    const __bf16* arow = &agg[lr][lk * 8];

    f32x4v acc0 = {0.f, 0.f, 0.f, 0.f};
    f32x4v acc1 = {0.f, 0.f, 0.f, 0.f};
    #pragma unroll 4
    for (int k0 = 0; k0 < KK; k0 += 32) {
        const bf16x8 a  = *(const bf16x8*)(arow + k0);   // ds_read_b128
        const bf16x8 b0 = *(const bf16x8*)(wr0 + k0);    // global b128, L2-hit
        const bf16x8 b1 = *(const bf16x8*)(wr1 + k0);
        acc0 = __builtin_amdgcn_mfma_f32_16x16x32_bf16(a, b0, acc0, 0, 0, 0);
        acc1 = __builtin_amdgcn_mfma_f32_16x16x32_bf16(a, b1, acc1, 0, 0, 0);
    }

    const float bv0 = bias[ct0 * 16 + lr];
    const float bv1 = bias[ct1 * 16 + lr];
    #pragma unroll
    for (int j = 0; j < 4; ++j) {
        const int row = lk * 4 + j;      // node within tile
        float* op = out + ((size_t)b * N_ + n0 + row) * O_;
        op[ct0 * 16 + lr] = fmaxf(acc0[j] + bv0, 0.f);
        op[ct1 * 16 + lr] = fmaxf(acc1[j] + bv1, 0.f);
    }
}

extern "C" void kernel_launch(void* const* d_in, const int* in_sizes, int n_in,
                              void* d_out, int out_size, void* d_ws, size_t ws_size,
                              hipStream_t stream) {
    const float* nf    = (const float*)d_in[0];  // node_features  [B,N,D] f32
    const int*   nbr   = (const int*)  d_in[1];  // neighbor_indices [B,R,N,K] i32
    const float* relk  = (const float*)d_in[2];  // relation_kernels [R,D,O] f32
    const float* selfk = (const float*)d_in[3];  // self_kernel [D,O] f32
    const float* bias  = (const float*)d_in[4];  // bias [O] f32
    float* outp = (float*)d_out;                 // [B,N,O] f32

    // workspace layout: bf16 padded table, then bf16 W^T
    __bf16* ptab = (__bf16*)d_ws;                              // B*NP1*D = 4,195,328 B
    __bf16* wtp  = (__bf16*)((char*)d_ws + (size_t)B_ * NP1 * D_ * 2);  // 163,840 B

    {
        const int total = B_ * NP1 * (D_ / 4);
        prep_table<<<(total + 255) / 256, 256, 0, stream>>>(nf, ptab);
    }
    prep_wt<<<(O_ * KK + 255) / 256, 256, 0, stream>>>(relk, selfk, wtp);

    dim3 grid(B_ * (N_ / TN));
    gcn_fused<<<grid, THREADS, 0, stream>>>(ptab, nbr, wtp, bias, outp);
}